// Round 9
// baseline (2240.297 us; speedup 1.0000x reference)
//
#include <hip/hip_runtime.h>
#include <stdint.h>
#include <stddef.h>

#define B_ 256
#define L_ 151
#define D_ 256
#define H_ 8
#define DH_ 32
#define FF_ 2048
#define NL_ 6
#define M_ (B_ * L_)      // 38656 = 302 * 128

typedef unsigned short ushort_t;
typedef __bf16 bf16x8 __attribute__((ext_vector_type(8)));
typedef float f32x4 __attribute__((ext_vector_type(4)));
typedef unsigned short us8 __attribute__((ext_vector_type(8)));

__device__ __forceinline__ float bf2f(ushort_t u) {
    union { unsigned int i; float f; } v;
    v.i = ((unsigned int)u) << 16;
    return v.f;
}
__device__ __forceinline__ ushort_t f2bf(float f) {
    union { float f; unsigned int i; } v;
    v.f = f;
    unsigned int x = v.i;
    return (ushort_t)((x + 0x7fffu + ((x >> 16) & 1u)) >> 16);
}

__device__ __forceinline__ void gld_lds16(const ushort_t* g, ushort_t* l) {
    __builtin_amdgcn_global_load_lds(
        (const __attribute__((address_space(1))) void*)g,
        (__attribute__((address_space(3))) void*)l,
        16, 0, 0);
}

// ---------------------------------------------------------------------------
// Input dtype detection (flag: 0 = bf16 inputs, 1 = fp32 inputs).
// ---------------------------------------------------------------------------
__global__ __launch_bounds__(256)
void detect_kernel(const unsigned int* __restrict__ w, int* __restrict__ flag)
{
    __shared__ int sh[256];
    int tid = threadIdx.x;
    int cnt = 0;
    for (int i = tid; i < 1024; i += 256) {
        unsigned int x = w[i];
        int e = (x >> 7) & 0xFF;
        cnt += (e >= 110 && e <= 140) ? 1 : 0;
    }
    sh[tid] = cnt;
    __syncthreads();
    for (int s = 128; s > 0; s >>= 1) {
        if (tid < s) sh[tid] += sh[tid + s];
        __syncthreads();
    }
    if (tid == 0) *flag = (sh[0] > 512) ? 0 : 1;
}

// ---------------------------------------------------------------------------
// Convert ALL weights/biases to bf16 in one launch (compile-time segment map).
// ---------------------------------------------------------------------------
struct WPtrs { const void* p[12]; };

#define WTOT 7890432

__global__ __launch_bounds__(256)
void cvt_all_kernel(WPtrs w, const int* __restrict__ flag, ushort_t* __restrict__ out)
{
    size_t i = (size_t)blockIdx.x * 256 + threadIdx.x;
    if (i >= WTOT) return;
    int a; size_t base;
    if      (i < 1179648) { a = 0;  base = 0; }
    else if (i < 1184256) { a = 1;  base = 1179648; }
    else if (i < 1577472) { a = 2;  base = 1184256; }
    else if (i < 1579008) { a = 3;  base = 1577472; }
    else if (i < 4724736) { a = 4;  base = 1579008; }
    else if (i < 4737024) { a = 5;  base = 4724736; }
    else if (i < 7882752) { a = 6;  base = 4737024; }
    else if (i < 7884288) { a = 7;  base = 7882752; }
    else if (i < 7885824) { a = 8;  base = 7884288; }
    else if (i < 7887360) { a = 9;  base = 7885824; }
    else if (i < 7888896) { a = 10; base = 7887360; }
    else                  { a = 11; base = 7888896; }
    size_t j = i - base;
    if (*flag) out[i] = f2bf(((const float*)w.p[a])[j]);
    else       out[i] = ((const ushort_t*)w.p[a])[j];
}

// src -> fp32 residual stream + bf16 GEMM copy.
__global__ __launch_bounds__(256)
void cvt_src_kernel(const void* __restrict__ in, const int* __restrict__ flag,
                    float* __restrict__ xf, ushort_t* __restrict__ xb)
{
    size_t i = (size_t)blockIdx.x * 256 + threadIdx.x;
    float v = (*flag) ? ((const float*)in)[i] : bf2f(((const ushort_t*)in)[i]);
    xf[i] = v;
    xb[i] = f2bf(v);
}

// xf -> d_out in the right dtype (runs after ALL x_b reads are done).
__global__ __launch_bounds__(256)
void cvt_out_kernel(const float* __restrict__ xf, const int* __restrict__ flag,
                    void* __restrict__ out)
{
    size_t i = ((size_t)blockIdx.x * 256 + threadIdx.x) * 4;
    float4 v = *(const float4*)(xf + i);
    if (*flag) {
        *(float4*)((float*)out + i) = v;
    } else {
        ushort4 uv;
        uv.x = f2bf(v.x); uv.y = f2bf(v.y); uv.z = f2bf(v.z); uv.w = f2bf(v.w);
        *(ushort4*)((ushort_t*)out + i) = uv;
    }
}

// ---------------------------------------------------------------------------
// GEMM (m97): 128x128 tile, 4 waves, BK=64, global_load_lds staging.
// bf16 store. Used for the QKV projection (N=768, K=256).
// ---------------------------------------------------------------------------
__global__ __launch_bounds__(256, 2)
void gemm_bt(const ushort_t* __restrict__ A, const ushort_t* __restrict__ Bw,
             const ushort_t* __restrict__ bias, ushort_t* __restrict__ Out,
             int N, int K, int lda)
{
    alignas(16) __shared__ ushort_t lsA[128 * 64];
    alignas(16) __shared__ ushort_t lsB[128 * 64];

    const int tid  = threadIdx.x;
    const int wave = tid >> 6;
    const int lane = tid & 63;
    const int row0 = blockIdx.y * 128;
    const int col0 = blockIdx.x * 128;

    const int wr   = (wave >> 1) * 64;
    const int wc   = (wave & 1) * 64;
    const int lm   = lane & 15;
    const int quad = lane >> 4;

    f32x4 acc[4][4];
#pragma unroll
    for (int i = 0; i < 4; ++i)
#pragma unroll
        for (int j = 0; j < 4; ++j)
            acc[i][j] = (f32x4){0.f, 0.f, 0.f, 0.f};

    for (int k0 = 0; k0 < K; k0 += 64) {
        __syncthreads();
#pragma unroll
        for (int it = 0; it < 4; ++it) {
            int c16 = (it * 4 + wave) * 64 + lane;
            int r   = c16 >> 3;
            int kc  = c16 & 7;
            const ushort_t* ga = A  + (size_t)(row0 + r) * lda + k0 + kc * 8;
            const ushort_t* gb = Bw + (size_t)(col0 + r) * K   + k0 + kc * 8;
            gld_lds16(ga, &lsA[(size_t)(it * 4 + wave) * 512]);
            gld_lds16(gb, &lsB[(size_t)(it * 4 + wave) * 512]);
        }
        __syncthreads();

#pragma unroll
        for (int kc = 0; kc < 2; ++kc) {
            bf16x8 af[4], bfr[4];
#pragma unroll
            for (int i = 0; i < 4; ++i) {
                af[i]  = *reinterpret_cast<const bf16x8*>(
                             &lsA[(wr + i * 16 + lm) * 64 + kc * 32 + quad * 8]);
                bfr[i] = *reinterpret_cast<const bf16x8*>(
                             &lsB[(wc + i * 16 + lm) * 64 + kc * 32 + quad * 8]);
            }
#pragma unroll
            for (int i = 0; i < 4; ++i)
#pragma unroll
                for (int j = 0; j < 4; ++j)
                    acc[i][j] = __builtin_amdgcn_mfma_f32_16x16x32_bf16(
                        af[i], bfr[j], acc[i][j], 0, 0, 0);
        }
    }

    float bvals[4];
#pragma unroll
    for (int j = 0; j < 4; ++j)
        bvals[j] = bf2f(bias[col0 + wc + j * 16 + lm]);

#pragma unroll
    for (int i = 0; i < 4; ++i) {
        int mrow = row0 + wr + i * 16 + quad * 4;
#pragma unroll
        for (int j = 0; j < 4; ++j) {
            int ncol = col0 + wc + j * 16 + lm;
#pragma unroll
            for (int r = 0; r < 4; ++r)
                Out[(size_t)(mrow + r) * N + ncol] = f2bf(acc[i][j][r] + bvals[j]);
        }
    }
}

// ---------------------------------------------------------------------------
// Out-projection + residual + FUSED LN1 (unchanged from v8/R8 -- passed).
// ---------------------------------------------------------------------------
__global__ __launch_bounds__(512, 2)
void oproj_ln_kernel(const ushort_t* __restrict__ A, const ushort_t* __restrict__ Bw,
                     const ushort_t* __restrict__ bias, float* __restrict__ xf,
                     const ushort_t* __restrict__ ls, const ushort_t* __restrict__ lb,
                     ushort_t* __restrict__ xb_out)
{
    alignas(16) __shared__ ushort_t lsA[128 * 64];   // 16 KB
    alignas(16) __shared__ ushort_t lsB[256 * 64];   // 32 KB

    const int tid  = threadIdx.x;
    const int wave = tid >> 6;        // 0..7
    const int lane = tid & 63;
    const int lm   = lane & 15;
    const int quad = lane >> 4;
    const int row0 = blockIdx.x * 128;

    const int wr = (wave & 1) * 64;   // row-group (2)
    const int wc = (wave >> 1) * 64;  // col-group (4)
    const int cg = wave >> 1;

    f32x4 acc[4][4];
#pragma unroll
    for (int i = 0; i < 4; ++i)
#pragma unroll
        for (int j = 0; j < 4; ++j)
            acc[i][j] = (f32x4){0.f, 0.f, 0.f, 0.f};

    for (int k0 = 0; k0 < 256; k0 += 64) {
        __syncthreads();
#pragma unroll
        for (int t = 0; t < 2; ++t) {              // A: 128 rows x 8 units
            int u = t * 512 + tid;
            int r = u >> 3, kc = u & 7;
            gld_lds16(A + (size_t)(row0 + r) * 768 + k0 + kc * 8, &lsA[(size_t)u * 8]);
        }
#pragma unroll
        for (int t = 0; t < 4; ++t) {              // B: 256 out-cols x 8 units
            int u = t * 512 + tid;
            int r = u >> 3, kc = u & 7;
            gld_lds16(Bw + (size_t)r * 256 + k0 + kc * 8, &lsB[(size_t)u * 8]);
        }
        __syncthreads();

#pragma unroll
        for (int kc = 0; kc < 2; ++kc) {
            bf16x8 af[4], bfr[4];
#pragma unroll
            for (int i = 0; i < 4; ++i) {
                af[i]  = *reinterpret_cast<const bf16x8*>(
                             &lsA[(wr + i * 16 + lm) * 64 + kc * 32 + quad * 8]);
                bfr[i] = *reinterpret_cast<const bf16x8*>(
                             &lsB[(wc + i * 16 + lm) * 64 + kc * 32 + quad * 8]);
            }
#pragma unroll
            for (int i = 0; i < 4; ++i)
#pragma unroll
                for (int j = 0; j < 4; ++j)
                    acc[i][j] = __builtin_amdgcn_mfma_f32_16x16x32_bf16(
                        af[i], bfr[j], acc[i][j], 0, 0, 0);
        }
    }

    __syncthreads();                  // lsA reads done -> reuse as partial buf
    float* Pf = (float*)lsA;          // [128 rows][4 cg][2] floats = 4 KB

    float bvals[4];
#pragma unroll
    for (int j = 0; j < 4; ++j)
        bvals[j] = bf2f(bias[wc + j * 16 + lm]);

    // pass 1: v = xf + acc + b; per-row partial sums -> LDS
#pragma unroll
    for (int i = 0; i < 4; ++i) {
#pragma unroll
        for (int r = 0; r < 4; ++r) {
            int lrow = wr + i * 16 + quad * 4 + r;
            size_t gbase = (size_t)(row0 + lrow) * 256;
            float s = 0.f, ss = 0.f;
#pragma unroll
            for (int j = 0; j < 4; ++j) {
                float v = xf[gbase + wc + j * 16 + lm] + acc[i][j][r] + bvals[j];
                acc[i][j][r] = v;
                s += v; ss += v * v;
            }
#pragma unroll
            for (int o = 1; o < 16; o <<= 1) {
                s  += __shfl_xor(s,  o, 64);
                ss += __shfl_xor(ss, o, 64);
            }
            if (lm == 0) {
                Pf[(lrow * 4 + cg) * 2]     = s;
                Pf[(lrow * 4 + cg) * 2 + 1] = ss;
            }
        }
    }
    __syncthreads();

    float lsv[4], lbv[4];
#pragma unroll
    for (int j = 0; j < 4; ++j) {
        lsv[j] = bf2f(ls[wc + j * 16 + lm]);
        lbv[j] = bf2f(lb[wc + j * 16 + lm]);
    }

    // pass 2: finalize LN, write xf fp32 + x_b bf16
#pragma unroll
    for (int i = 0; i < 4; ++i) {
#pragma unroll
        for (int r = 0; r < 4; ++r) {
            int lrow = wr + i * 16 + quad * 4 + r;
            float S = 0.f, SS = 0.f;
#pragma unroll
            for (int c4 = 0; c4 < 4; ++c4) {
                S  += Pf[(lrow * 4 + c4) * 2];
                SS += Pf[(lrow * 4 + c4) * 2 + 1];
            }
            float mu   = S * (1.f / 256.f);
            float var  = SS * (1.f / 256.f) - mu * mu;
            float rstd = rsqrtf(var + 1e-5f);
            size_t gbase = (size_t)(row0 + lrow) * 256;
#pragma unroll
            for (int j = 0; j < 4; ++j) {
                float y = (acc[i][j][r] - mu) * rstd * lsv[j] + lbv[j];
                size_t idx = gbase + wc + j * 16 + lm;
                xf[idx]     = y;
                xb_out[idx] = f2bf(y);
            }
        }
    }
}

// ---------------------------------------------------------------------------
// Fused FFN + LN2, v9: software-pipelined single-barrier chunks.
// R8: v8 = 202us, MfmaUtil 16%, chunk ~7000cyc vs ~3600 LDS + ~620 MFMA.
// R3 proved the DMA drain isn't the cost -> residual = 2x per-chunk
// 8-wave lockstep. v9: iteration c does {FF1(c+1) -> Ps[(c+1)&1]; FF2(c)
// <- Ps[c&1]} with ONE barrier (64 -> 32 lockstep points), and a 64-MFMA
// independent region for the scheduler.
// Hazard ledger (all protected by the single end-of-iter __syncthreads):
//  - stageW1(c+2) -> W1c[c&1]: last read by FF1(c+1->c) at iter c-1  OK
//  - stageW2(c+1) -> W2c[(c+1)&1]: last read by FF2(c-1) at iter c-1 OK
//  - FF1(c+1) reads W1c[(c+1)&1] staged at iter c-1, drained by barrier OK
//  - FF2(c) reads W2c[c&1] staged at iter c-1 OK; Ps[c&1] written iter c-1 OK
//  - Ps[(c+1)&1] write vs Ps[c&1] read: disjoint buffers (intra-iter) OK
// Ps: stride-64 + XOR ((row&7)<<3) swizzle (pad-72 doesn't fit dbuf'd);
// pa-read XOR folds to sw since row&7 == lm&7. LDS = 64+64+32 KB = 160 KiB
// exact (pool limit).
// ---------------------------------------------------------------------------
__global__ __launch_bounds__(512, 2)
void ffn_kernel(const ushort_t* __restrict__ xb, const ushort_t* __restrict__ W1,
                const ushort_t* __restrict__ b1, const ushort_t* __restrict__ W2,
                const ushort_t* __restrict__ b2, float* __restrict__ xf,
                const ushort_t* __restrict__ ls, const ushort_t* __restrict__ lb,
                ushort_t* __restrict__ xb_out, int is_final)
{
    alignas(16) __shared__ ushort_t W1c[2][64 * 256];   // 32 KB each, swizzled
    alignas(16) __shared__ ushort_t W2c[2][256 * 64];   // 32 KB each, swizzled
    alignas(16) __shared__ ushort_t Ps[2][128 * 64];    // 16 KB each, XOR-swizzled

    const int tid  = threadIdx.x;
    const int wave = tid >> 6;
    const int lane = tid & 63;
    const int lm   = lane & 15;
    const int quad = lane >> 4;
    const int row0 = blockIdx.x * 128;
    const int sw   = (lm & 7) << 3;   // read-side XOR swizzle (ushort units)

    const int pr = (wave & 1) * 64;   // FF1: wave P-row base (64-row tile)
    const int pc = (wave >> 1) * 16;  // FF1: wave P-col base (16-col tile)
    const int fr = (wave & 1) * 64;   // FF2: wave out-row base
    const int fc = (wave >> 1) * 64;  // FF2: wave out-col base
    const int cg = wave >> 1;

    // ---- preload x A-frags (rows pr..pr+63, full K=256) into registers ----
    bf16x8 xa[4][8];
#pragma unroll
    for (int i = 0; i < 4; ++i)
#pragma unroll
        for (int kk = 0; kk < 8; ++kk)
            xa[i][kk] = *(const bf16x8*)(xb + (size_t)(row0 + pr + i * 16 + lm) * 256
                                            + kk * 32 + quad * 8);

    f32x4 acc[4][4];
#pragma unroll
    for (int i = 0; i < 4; ++i)
#pragma unroll
        for (int j = 0; j < 4; ++j)
            acc[i][j] = (f32x4){0.f, 0.f, 0.f, 0.f};

    // ---- weight staging halves: linear LDS dest, pre-swizzled global src ----
    auto stageW1c = [&](int c, int buf) {
        const ushort_t* g1 = W1 + (size_t)c * 64 * 256;
#pragma unroll
        for (int t = 0; t < 4; ++t) {
            int idx = t * 512 + tid;                 // 16B chunk id, 0..2047
            int s1  = idx ^ ((idx >> 5) & 7);        // swizzled source unit
            gld_lds16(g1 + (size_t)s1 * 8, &W1c[buf][(size_t)(t * 512 + wave * 64) * 8]);
        }
    };
    auto stageW2c = [&](int c, int buf) {
#pragma unroll
        for (int t = 0; t < 4; ++t) {
            int idx = t * 512 + tid;                 // row=idx>>3, k8=idx&7
            int k8  = (idx & 7) ^ ((idx >> 3) & 7);  // swizzled k-slot
            const ushort_t* g2 = W2 + (size_t)(idx >> 3) * 2048 + c * 64 + k8 * 8;
            gld_lds16(g2, &W2c[buf][(size_t)(t * 512 + wave * 64) * 8]);
        }
    };

    // ---- FF1 for chunk cc -> Ps[buf] (XOR-swizzled write) ----
    auto doFF1 = [&](int cc, int buf) {
        f32x4 p[4];
#pragma unroll
        for (int i = 0; i < 4; ++i)
            p[i] = (f32x4){0.f, 0.f, 0.f, 0.f};
#pragma unroll
        for (int kk = 0; kk < 8; ++kk) {
            bf16x8 wb = *(const bf16x8*)&W1c[cc & 1][((pc + lm) * 256 + kk * 32 + quad * 8) ^ sw];
#pragma unroll
            for (int i = 0; i < 4; ++i)
                p[i] = __builtin_amdgcn_mfma_f32_16x16x32_bf16(xa[i][kk], wb, p[i], 0, 0, 0);
        }
        float bv = bf2f(b1[cc * 64 + pc + lm]);
#pragma unroll
        for (int i = 0; i < 4; ++i)
#pragma unroll
            for (int r = 0; r < 4; ++r) {
                int prow = pr + i * 16 + quad * 4 + r;
                Ps[buf][(prow * 64 + pc + lm) ^ ((prow & 7) << 3)] =
                    f2bf(fmaxf(p[i][r] + bv, 0.f));
            }
    };

    // ---- prologue: W1(0), W2(0), W1(1); FF1(0) ----
    stageW1c(0, 0);
    stageW2c(0, 0);
    stageW1c(1, 1);
    __syncthreads();
    doFF1(0, 0);
    __syncthreads();

    for (int c = 0; c < 32; ++c) {
        if (c + 2 < 32) stageW1c(c + 2, c & 1);
        if (c + 1 < 32) stageW2c(c + 1, (c + 1) & 1);
        if (c + 1 < 32) doFF1(c + 1, (c + 1) & 1);

        // ---- FF2(c): acc += P(c) @ W2(c)^T ----
#pragma unroll
        for (int ks = 0; ks < 2; ++ks) {
            bf16x8 pa[4];
#pragma unroll
            for (int i = 0; i < 4; ++i)
                pa[i] = *(const bf16x8*)&Ps[c & 1][(((fr + i * 16 + lm) * 64) + ks * 32 + quad * 8) ^ sw];
#pragma unroll
            for (int j = 0; j < 4; ++j) {
                bf16x8 w2b = *(const bf16x8*)&W2c[c & 1][((fc + j * 16 + lm) * 64 + ks * 32 + quad * 8) ^ sw];
#pragma unroll
                for (int i = 0; i < 4; ++i)
                    acc[i][j] = __builtin_amdgcn_mfma_f32_16x16x32_bf16(pa[i], w2b, acc[i][j], 0, 0, 0);
            }
        }
        if (c + 1 < 32) __syncthreads();
    }

    // ---- fused LN2 epilogue (unchanged from v8) ----
    __syncthreads();
    float* Pf = (float*)&Ps[0][0];    // [128 rows][4 cg][2] floats = 4 KB

    float b2v[4];
#pragma unroll
    for (int j = 0; j < 4; ++j)
        b2v[j] = bf2f(b2[fc + j * 16 + lm]);

    // pass 1: v = xf + acc + b2; per-row partial sums -> LDS
#pragma unroll
    for (int i = 0; i < 4; ++i) {
#pragma unroll
        for (int r = 0; r < 4; ++r) {
            int lrow = fr + i * 16 + quad * 4 + r;
            size_t gbase = (size_t)(row0 + lrow) * 256;
            float s = 0.f, ss = 0.f;
#pragma unroll
            for (int j = 0; j < 4; ++j) {
                float v = xf[gbase + fc + j * 16 + lm] + acc[i][j][r] + b2v[j];
                acc[i][j][r] = v;
                s += v; ss += v * v;
            }
#pragma unroll
            for (int o = 1; o < 16; o <<= 1) {
                s  += __shfl_xor(s,  o, 64);
                ss += __shfl_xor(ss, o, 64);
            }
            if (lm == 0) {
                Pf[(lrow * 4 + cg) * 2]     = s;
                Pf[(lrow * 4 + cg) * 2 + 1] = ss;
            }
        }
    }
    __syncthreads();

    float lsv[4], lbv[4];
#pragma unroll
    for (int j = 0; j < 4; ++j) {
        lsv[j] = bf2f(ls[fc + j * 16 + lm]);
        lbv[j] = bf2f(lb[fc + j * 16 + lm]);
    }

    // pass 2: finalize LN2; write xf (+ x_b for non-final layers)
#pragma unroll
    for (int i = 0; i < 4; ++i) {
#pragma unroll
        for (int r = 0; r < 4; ++r) {
            int lrow = fr + i * 16 + quad * 4 + r;
            float S = 0.f, SS = 0.f;
#pragma unroll
            for (int c4 = 0; c4 < 4; ++c4) {
                S  += Pf[(lrow * 4 + c4) * 2];
                SS += Pf[(lrow * 4 + c4) * 2 + 1];
            }
            float mu   = S * (1.f / 256.f);
            float var  = SS * (1.f / 256.f) - mu * mu;
            float rstd = rsqrtf(var + 1e-5f);
            size_t gbase = (size_t)(row0 + lrow) * 256;
#pragma unroll
            for (int j = 0; j < 4; ++j) {
                float y = (acc[i][j][r] - mu) * rstd * lsv[j] + lbv[j];
                size_t idx = gbase + fc + j * 16 + lm;
                xf[idx] = y;
                if (!is_final) xb_out[idx] = f2bf(y);
            }
        }
    }
}

// ---------------------------------------------------------------------------
// MFMA block-diagonal attention, wave-per-head, zero block barriers.
// ---------------------------------------------------------------------------
__constant__ int c_starts[6] = {0, 50, 67, 84, 101, 151};

__global__ __launch_bounds__(256)
void attn_kernel(ushort_t* __restrict__ qkv)
{
    alignas(16) __shared__ ushort_t Vt[4][32 * 72];  // V^T: [dh][key]
    alignas(16) __shared__ ushort_t Pss[4][16 * 72]; // P strip: [row][key]

    const int b    = blockIdx.x / 5;
    const int blk  = blockIdx.x % 5;
    const int a0   = c_starts[blk];
    const int n    = c_starts[blk + 1] - a0;
    const int wave = threadIdx.x >> 6;
    const int lane = threadIdx.x & 63;
    const int lm   = lane & 15;
    const int quad = lane >> 4;
    const float scale = 0.17677669529663687f;  // 1/sqrt(32)

    const size_t rowbase = (size_t)b * L_ + a0;

    for (int hi = 0; hi < 2; ++hi) {
        const int h = wave + hi * 4;
        const int hoff = h * 32;

#pragma unroll
        for (int it = 0; it < 4; ++it) {
            int gidx = it * 64 + lane;
            int c    = gidx >> 2;
            int dcc  = (gidx & 3) * 8;
            us8 v = *(const us8*)(qkv + (rowbase + c) * 768 + 512 + hoff + dcc);
            if (c >= n) v = (us8){0,0,0,0,0,0,0,0};
#pragma unroll
            for (int j = 0; j < 8; ++j)
                Vt[wave][(dcc + j) * 72 + c] = v[j];
        }

        bf16x8 kb[4];
#pragma unroll
        for (int j = 0; j < 4; ++j)
            kb[j] = *(const bf16x8*)(qkv + (rowbase + 16 * j + lm) * 768 + 256 + hoff + quad * 8);

        bf16x8 vb[2][2];
#pragma unroll
        for (int t = 0; t < 2; ++t)
#pragma unroll
            for (int kc = 0; kc < 2; ++kc)
                vb[t][kc] = *(const bf16x8*)&Vt[wave][(16 * t + lm) * 72 + kc * 32 + quad * 8];

        for (int i = 0; i < 4 && 16 * i < n; ++i) {
            bf16x8 qa = *(const bf16x8*)(qkv + (rowbase + 16 * i + lm) * 768 + hoff + quad * 8);

            f32x4 s[4];
#pragma unroll
            for (int j = 0; j < 4; ++j)
                s[j] = __builtin_amdgcn_mfma_f32_16x16x32_bf16(
                    qa, kb[j], (f32x4){0.f, 0.f, 0.f, 0.f}, 0, 0, 0);

#pragma unroll
            for (int j = 0; j < 4; ++j) {
                bool valid = (16 * j + lm) < n;
#pragma unroll
                for (int r = 0; r < 4; ++r)
                    s[j][r] = valid ? s[j][r] * scale : -1e30f;
            }

            float inv[4];
#pragma unroll
            for (int r = 0; r < 4; ++r) {
                float mx = fmaxf(fmaxf(s[0][r], s[1][r]), fmaxf(s[2][r], s[3][r]));
#pragma unroll
                for (int o2 = 1; o2 < 16; o2 <<= 1) mx = fmaxf(mx, __shfl_xor(mx, o2, 64));
                float sum = 0.f;
#pragma unroll
                for (int j = 0; j < 4; ++j) {
                    float ev = __expf(s[j][r] - mx);
                    s[j][r] = ev;
                    sum += ev;
                }
#pragma unroll
                for (int o2 = 1; o2 < 16; o2 <<= 1) sum += __shfl_xor(sum, o2, 64);
                inv[r] = 1.0f / sum;
            }

#pragma unroll
            for (int j = 0; j < 4; ++j)
#pragma unroll
                for (int r = 0; r < 4; ++r)
                    Pss[wave][(quad * 4 + r) * 72 + 16 * j + lm] = f2bf(s[j][r]);

            bf16x8 pa0 = *(const bf16x8*)&Pss[wave][lm * 72 + quad * 8];
            bf16x8 pa1 = *(const bf16x8*)&Pss[wave][lm * 72 + 32 + quad * 8];

            f32x4 o[2];
#pragma unroll
            for (int t = 0; t < 2; ++t) {
                o[t] = __builtin_amdgcn_mfma_f32_16x16x32_bf16(
                    pa0, vb[t][0], (f32x4){0.f, 0.f, 0.f, 0.f}, 0, 0, 0);
                o[t] = __builtin_amdgcn_mfma_f32_16x16x32_bf16(
                    pa1, vb[t][1], o[t], 0, 0, 0);
            }

#pragma unroll
            for (int r = 0; r < 4; ++r) {
                int m = 16 * i + quad * 4 + r;
                if (m < n) {
#pragma unroll
                    for (int t = 0; t < 2; ++t)
                        qkv[(rowbase + m) * 768 + hoff + 16 * t + lm] =
                            f2bf(o[t][r] * inv[r]);
                }
            }
        }
    }
}

// ---------------------------------------------------------------------------
// Workspace: x_f32 39.58MB | U 59.38MB | Wbf 15.78MB | flag = ~114.8MB.
// x_b bf16 residual copy lives in d_out; cvt_out writes the real answer.
// ---------------------------------------------------------------------------
extern "C" void kernel_launch(void* const* d_in, const int* in_sizes, int n_in,
                              void* d_out, int out_size, void* d_ws, size_t ws_size,
                              hipStream_t stream)
{
    char* ws = (char*)d_ws;
    size_t o = 0;
    float*    x_f32 = (float*)(ws + o);    o += (size_t)M_ * D_ * 4;
    ushort_t* U     = (ushort_t*)(ws + o); o += (size_t)M_ * 768 * 2;
    ushort_t* Wbf   = (ushort_t*)(ws + o); o += (size_t)WTOT * 2;
    int*      flag  = (int*)(ws + o);      o += 256;
    ushort_t* x_b   = (ushort_t*)d_out;
    (void)ws_size; (void)in_sizes; (void)n_in; (void)out_size;

    detect_kernel<<<1, 256, 0, stream>>>((const unsigned int*)d_in[0], flag);

    WPtrs wp;
    for (int a = 0; a < 12; ++a) wp.p[a] = d_in[a + 1];
    cvt_all_kernel<<<(WTOT + 255) / 256, 256, 0, stream>>>(wp, flag, Wbf);

    const ushort_t* qkv_w = Wbf + 0;
    const ushort_t* qkv_b = Wbf + 1179648;
    const ushort_t* out_w = Wbf + 1184256;
    const ushort_t* out_b = Wbf + 1577472;
    const ushort_t* ff1_w = Wbf + 1579008;
    const ushort_t* ff1_b = Wbf + 4724736;
    const ushort_t* ff2_w = Wbf + 4737024;
    const ushort_t* ff2_b = Wbf + 7882752;
    const ushort_t* ln1_s = Wbf + 7884288;
    const ushort_t* ln1_b = Wbf + 7885824;
    const ushort_t* ln2_s = Wbf + 7887360;
    const ushort_t* ln2_b = Wbf + 7888896;

    cvt_src_kernel<<<(M_ * D_) / 256, 256, 0, stream>>>(d_in[0], flag, x_f32, x_b);

    for (int i = 0; i < NL_; ++i) {
        // QKV projection -> U [M,768] bf16
        gemm_bt<<<dim3(6, M_ / 128), 256, 0, stream>>>(
            x_b, qkv_w + (size_t)i * 768 * D_, qkv_b + (size_t)i * 768, U,
            768, D_, D_);
        // MFMA block-diagonal attention; ctx overwrites q columns of U
        attn_kernel<<<B_ * 5, 256, 0, stream>>>(U);
        // out projection + residual + fused LN1: xf = LN1(xf + ctx@W^T + b)
        oproj_ln_kernel<<<M_ / 128, 512, 0, stream>>>(
            U, out_w + (size_t)i * D_ * D_, out_b + (size_t)i * D_, x_f32,
            ln1_s + (size_t)i * D_, ln1_b + (size_t)i * D_, x_b);
        // fused FFN + LN2: xf = LN2(xf + W2@relu(W1@x_b+b1)+b2)
        ffn_kernel<<<M_ / 128, 512, 0, stream>>>(
            x_b, ff1_w + (size_t)i * FF_ * D_, ff1_b + (size_t)i * FF_,
            ff2_w + (size_t)i * D_ * FF_, ff2_b + (size_t)i * D_, x_f32,
            ln2_s + (size_t)i * D_, ln2_b + (size_t)i * D_,
            x_b, (i == NL_ - 1) ? 1 : 0);
    }
    // final output conversion (after ALL x_b reads are complete)
    cvt_out_kernel<<<(M_ * D_) / 1024, 256, 0, stream>>>(x_f32, flag, d_out);
}

// Round 10
// 1940.776 us; speedup vs baseline: 1.1543x; 1.1543x over previous
//
#include <hip/hip_runtime.h>
#include <stdint.h>
#include <stddef.h>

#define B_ 256
#define L_ 151
#define D_ 256
#define H_ 8
#define DH_ 32
#define FF_ 2048
#define NL_ 6
#define M_ (B_ * L_)      // 38656 = 302 * 128

typedef unsigned short ushort_t;
typedef __bf16 bf16x8 __attribute__((ext_vector_type(8)));
typedef float f32x4 __attribute__((ext_vector_type(4)));
typedef unsigned short us8 __attribute__((ext_vector_type(8)));

__device__ __forceinline__ float bf2f(ushort_t u) {
    union { unsigned int i; float f; } v;
    v.i = ((unsigned int)u) << 16;
    return v.f;
}
__device__ __forceinline__ ushort_t f2bf(float f) {
    union { float f; unsigned int i; } v;
    v.f = f;
    unsigned int x = v.i;
    return (ushort_t)((x + 0x7fffu + ((x >> 16) & 1u)) >> 16);
}

__device__ __forceinline__ void gld_lds16(const ushort_t* g, ushort_t* l) {
    __builtin_amdgcn_global_load_lds(
        (const __attribute__((address_space(1))) void*)g,
        (__attribute__((address_space(3))) void*)l,
        16, 0, 0);
}

// ---------------------------------------------------------------------------
// Input dtype detection (flag: 0 = bf16 inputs, 1 = fp32 inputs).
// ---------------------------------------------------------------------------
__global__ __launch_bounds__(256)
void detect_kernel(const unsigned int* __restrict__ w, int* __restrict__ flag)
{
    __shared__ int sh[256];
    int tid = threadIdx.x;
    int cnt = 0;
    for (int i = tid; i < 1024; i += 256) {
        unsigned int x = w[i];
        int e = (x >> 7) & 0xFF;
        cnt += (e >= 110 && e <= 140) ? 1 : 0;
    }
    sh[tid] = cnt;
    __syncthreads();
    for (int s = 128; s > 0; s >>= 1) {
        if (tid < s) sh[tid] += sh[tid + s];
        __syncthreads();
    }
    if (tid == 0) *flag = (sh[0] > 512) ? 0 : 1;
}

// ---------------------------------------------------------------------------
// Convert ALL weights/biases to bf16 in one launch (compile-time segment map).
// ---------------------------------------------------------------------------
struct WPtrs { const void* p[12]; };

#define WTOT 7890432

__global__ __launch_bounds__(256)
void cvt_all_kernel(WPtrs w, const int* __restrict__ flag, ushort_t* __restrict__ out)
{
    size_t i = (size_t)blockIdx.x * 256 + threadIdx.x;
    if (i >= WTOT) return;
    int a; size_t base;
    if      (i < 1179648) { a = 0;  base = 0; }
    else if (i < 1184256) { a = 1;  base = 1179648; }
    else if (i < 1577472) { a = 2;  base = 1184256; }
    else if (i < 1579008) { a = 3;  base = 1577472; }
    else if (i < 4724736) { a = 4;  base = 1579008; }
    else if (i < 4737024) { a = 5;  base = 4724736; }
    else if (i < 7882752) { a = 6;  base = 4737024; }
    else if (i < 7884288) { a = 7;  base = 7882752; }
    else if (i < 7885824) { a = 8;  base = 7884288; }
    else if (i < 7887360) { a = 9;  base = 7885824; }
    else if (i < 7888896) { a = 10; base = 7887360; }
    else                  { a = 11; base = 7888896; }
    size_t j = i - base;
    if (*flag) out[i] = f2bf(((const float*)w.p[a])[j]);
    else       out[i] = ((const ushort_t*)w.p[a])[j];
}

// src -> fp32 residual stream + bf16 GEMM copy.
__global__ __launch_bounds__(256)
void cvt_src_kernel(const void* __restrict__ in, const int* __restrict__ flag,
                    float* __restrict__ xf, ushort_t* __restrict__ xb)
{
    size_t i = (size_t)blockIdx.x * 256 + threadIdx.x;
    float v = (*flag) ? ((const float*)in)[i] : bf2f(((const ushort_t*)in)[i]);
    xf[i] = v;
    xb[i] = f2bf(v);
}

// xf -> d_out in the right dtype (runs after ALL x_b reads are done).
__global__ __launch_bounds__(256)
void cvt_out_kernel(const float* __restrict__ xf, const int* __restrict__ flag,
                    void* __restrict__ out)
{
    size_t i = ((size_t)blockIdx.x * 256 + threadIdx.x) * 4;
    float4 v = *(const float4*)(xf + i);
    if (*flag) {
        *(float4*)((float*)out + i) = v;
    } else {
        ushort4 uv;
        uv.x = f2bf(v.x); uv.y = f2bf(v.y); uv.z = f2bf(v.z); uv.w = f2bf(v.w);
        *(ushort4*)((ushort_t*)out + i) = uv;
    }
}

// ---------------------------------------------------------------------------
// QKV GEMM, R10: 128x256 tile, 512 thr (8 waves), K=256 -- the exact gemm
// core proven inside oproj_ln_kernel (R8), minus the LN epilogue.
// Replaces the 128x128 gemm_bt: grid 1812 -> 906 blocks (7.1 -> 3.5 rounds),
// A-tile staged bytes per output halved. bf16 store to U [M,768].
// ---------------------------------------------------------------------------
__global__ __launch_bounds__(512, 2)
void qkv_gemm(const ushort_t* __restrict__ A, const ushort_t* __restrict__ Bw,
              const ushort_t* __restrict__ bias, ushort_t* __restrict__ Out)
{
    alignas(16) __shared__ ushort_t lsA[128 * 64];   // 16 KB
    alignas(16) __shared__ ushort_t lsB[256 * 64];   // 32 KB

    const int tid  = threadIdx.x;
    const int wave = tid >> 6;        // 0..7
    const int lane = tid & 63;
    const int lm   = lane & 15;
    const int quad = lane >> 4;
    const int row0 = blockIdx.y * 128;
    const int col0 = blockIdx.x * 256;

    const int wr = (wave & 1) * 64;   // row-group (2)
    const int wc = (wave >> 1) * 64;  // col-group (4)

    f32x4 acc[4][4];
#pragma unroll
    for (int i = 0; i < 4; ++i)
#pragma unroll
        for (int j = 0; j < 4; ++j)
            acc[i][j] = (f32x4){0.f, 0.f, 0.f, 0.f};

    for (int k0 = 0; k0 < 256; k0 += 64) {
        __syncthreads();
#pragma unroll
        for (int t = 0; t < 2; ++t) {              // A: 128 rows x 8 units
            int u = t * 512 + tid;
            int r = u >> 3, kc = u & 7;
            gld_lds16(A + (size_t)(row0 + r) * 256 + k0 + kc * 8, &lsA[(size_t)u * 8]);
        }
#pragma unroll
        for (int t = 0; t < 4; ++t) {              // B: 256 out-cols x 8 units
            int u = t * 512 + tid;
            int r = u >> 3, kc = u & 7;
            gld_lds16(Bw + (size_t)(col0 + r) * 256 + k0 + kc * 8, &lsB[(size_t)u * 8]);
        }
        __syncthreads();

#pragma unroll
        for (int kc = 0; kc < 2; ++kc) {
            bf16x8 af[4], bfr[4];
#pragma unroll
            for (int i = 0; i < 4; ++i) {
                af[i]  = *reinterpret_cast<const bf16x8*>(
                             &lsA[(wr + i * 16 + lm) * 64 + kc * 32 + quad * 8]);
                bfr[i] = *reinterpret_cast<const bf16x8*>(
                             &lsB[(wc + i * 16 + lm) * 64 + kc * 32 + quad * 8]);
            }
#pragma unroll
            for (int i = 0; i < 4; ++i)
#pragma unroll
                for (int j = 0; j < 4; ++j)
                    acc[i][j] = __builtin_amdgcn_mfma_f32_16x16x32_bf16(
                        af[i], bfr[j], acc[i][j], 0, 0, 0);
        }
    }

    float bvals[4];
#pragma unroll
    for (int j = 0; j < 4; ++j)
        bvals[j] = bf2f(bias[col0 + wc + j * 16 + lm]);

#pragma unroll
    for (int i = 0; i < 4; ++i) {
        int mrow = row0 + wr + i * 16 + quad * 4;
#pragma unroll
        for (int j = 0; j < 4; ++j) {
            int ncol = col0 + wc + j * 16 + lm;
#pragma unroll
            for (int r = 0; r < 4; ++r)
                Out[(size_t)(mrow + r) * 768 + ncol] = f2bf(acc[i][j][r] + bvals[j]);
        }
    }
}

// ---------------------------------------------------------------------------
// Out-projection + residual + FUSED LN1 (unchanged from R8 -- passed).
// ---------------------------------------------------------------------------
__global__ __launch_bounds__(512, 2)
void oproj_ln_kernel(const ushort_t* __restrict__ A, const ushort_t* __restrict__ Bw,
                     const ushort_t* __restrict__ bias, float* __restrict__ xf,
                     const ushort_t* __restrict__ ls, const ushort_t* __restrict__ lb,
                     ushort_t* __restrict__ xb_out)
{
    alignas(16) __shared__ ushort_t lsA[128 * 64];   // 16 KB
    alignas(16) __shared__ ushort_t lsB[256 * 64];   // 32 KB

    const int tid  = threadIdx.x;
    const int wave = tid >> 6;        // 0..7
    const int lane = tid & 63;
    const int lm   = lane & 15;
    const int quad = lane >> 4;
    const int row0 = blockIdx.x * 128;

    const int wr = (wave & 1) * 64;   // row-group (2)
    const int wc = (wave >> 1) * 64;  // col-group (4)
    const int cg = wave >> 1;

    f32x4 acc[4][4];
#pragma unroll
    for (int i = 0; i < 4; ++i)
#pragma unroll
        for (int j = 0; j < 4; ++j)
            acc[i][j] = (f32x4){0.f, 0.f, 0.f, 0.f};

    for (int k0 = 0; k0 < 256; k0 += 64) {
        __syncthreads();
#pragma unroll
        for (int t = 0; t < 2; ++t) {              // A: 128 rows x 8 units
            int u = t * 512 + tid;
            int r = u >> 3, kc = u & 7;
            gld_lds16(A + (size_t)(row0 + r) * 768 + k0 + kc * 8, &lsA[(size_t)u * 8]);
        }
#pragma unroll
        for (int t = 0; t < 4; ++t) {              // B: 256 out-cols x 8 units
            int u = t * 512 + tid;
            int r = u >> 3, kc = u & 7;
            gld_lds16(Bw + (size_t)r * 256 + k0 + kc * 8, &lsB[(size_t)u * 8]);
        }
        __syncthreads();

#pragma unroll
        for (int kc = 0; kc < 2; ++kc) {
            bf16x8 af[4], bfr[4];
#pragma unroll
            for (int i = 0; i < 4; ++i) {
                af[i]  = *reinterpret_cast<const bf16x8*>(
                             &lsA[(wr + i * 16 + lm) * 64 + kc * 32 + quad * 8]);
                bfr[i] = *reinterpret_cast<const bf16x8*>(
                             &lsB[(wc + i * 16 + lm) * 64 + kc * 32 + quad * 8]);
            }
#pragma unroll
            for (int i = 0; i < 4; ++i)
#pragma unroll
                for (int j = 0; j < 4; ++j)
                    acc[i][j] = __builtin_amdgcn_mfma_f32_16x16x32_bf16(
                        af[i], bfr[j], acc[i][j], 0, 0, 0);
        }
    }

    __syncthreads();                  // lsA reads done -> reuse as partial buf
    float* Pf = (float*)lsA;          // [128 rows][4 cg][2] floats = 4 KB

    float bvals[4];
#pragma unroll
    for (int j = 0; j < 4; ++j)
        bvals[j] = bf2f(bias[wc + j * 16 + lm]);

    // pass 1: v = xf + acc + b; per-row partial sums -> LDS
#pragma unroll
    for (int i = 0; i < 4; ++i) {
#pragma unroll
        for (int r = 0; r < 4; ++r) {
            int lrow = wr + i * 16 + quad * 4 + r;
            size_t gbase = (size_t)(row0 + lrow) * 256;
            float s = 0.f, ss = 0.f;
#pragma unroll
            for (int j = 0; j < 4; ++j) {
                float v = xf[gbase + wc + j * 16 + lm] + acc[i][j][r] + bvals[j];
                acc[i][j][r] = v;
                s += v; ss += v * v;
            }
#pragma unroll
            for (int o = 1; o < 16; o <<= 1) {
                s  += __shfl_xor(s,  o, 64);
                ss += __shfl_xor(ss, o, 64);
            }
            if (lm == 0) {
                Pf[(lrow * 4 + cg) * 2]     = s;
                Pf[(lrow * 4 + cg) * 2 + 1] = ss;
            }
        }
    }
    __syncthreads();

    float lsv[4], lbv[4];
#pragma unroll
    for (int j = 0; j < 4; ++j) {
        lsv[j] = bf2f(ls[wc + j * 16 + lm]);
        lbv[j] = bf2f(lb[wc + j * 16 + lm]);
    }

    // pass 2: finalize LN, write xf fp32 + x_b bf16
#pragma unroll
    for (int i = 0; i < 4; ++i) {
#pragma unroll
        for (int r = 0; r < 4; ++r) {
            int lrow = wr + i * 16 + quad * 4 + r;
            float S = 0.f, SS = 0.f;
#pragma unroll
            for (int c4 = 0; c4 < 4; ++c4) {
                S  += Pf[(lrow * 4 + c4) * 2];
                SS += Pf[(lrow * 4 + c4) * 2 + 1];
            }
            float mu   = S * (1.f / 256.f);
            float var  = SS * (1.f / 256.f) - mu * mu;
            float rstd = rsqrtf(var + 1e-5f);
            size_t gbase = (size_t)(row0 + lrow) * 256;
#pragma unroll
            for (int j = 0; j < 4; ++j) {
                float y = (acc[i][j][r] - mu) * rstd * lsv[j] + lbv[j];
                size_t idx = gbase + wc + j * 16 + lm;
                xf[idx]     = y;
                xb_out[idx] = f2bf(y);
            }
        }
    }
}

// ---------------------------------------------------------------------------
// Fused FFN + LN2: EXACT R8 version (202us, proven). R9's single-barrier
// pipeline regressed (250us: compiler serialized the merged region with
// conservative lgkmcnt waits across the two Ps buffers). Barrier-count is
// a three-times-refuted axis (R3/R6/R9) -- this loop is at its floor.
// ---------------------------------------------------------------------------
__global__ __launch_bounds__(512, 2)
void ffn_kernel(const ushort_t* __restrict__ xb, const ushort_t* __restrict__ W1,
                const ushort_t* __restrict__ b1, const ushort_t* __restrict__ W2,
                const ushort_t* __restrict__ b2, float* __restrict__ xf,
                const ushort_t* __restrict__ ls, const ushort_t* __restrict__ lb,
                ushort_t* __restrict__ xb_out, int is_final)
{
    alignas(16) __shared__ ushort_t W1c[2][64 * 256];   // 32 KB each, swizzled
    alignas(16) __shared__ ushort_t W2c[2][256 * 64];   // 32 KB each, swizzled
    alignas(16) __shared__ ushort_t Ps[128 * 72];       // 18 KB (also LN partials)

    const int tid  = threadIdx.x;
    const int wave = tid >> 6;
    const int lane = tid & 63;
    const int lm   = lane & 15;
    const int quad = lane >> 4;
    const int row0 = blockIdx.x * 128;
    const int sw   = (lm & 7) << 3;   // read-side XOR swizzle (ushort units)

    const int pr = (wave & 1) * 64;   // FF1: wave P-row base (64-row tile)
    const int pc = (wave >> 1) * 16;  // FF1: wave P-col base (16-col tile)
    const int fr = (wave & 1) * 64;   // FF2: wave out-row base
    const int fc = (wave >> 1) * 64;  // FF2: wave out-col base
    const int cg = wave >> 1;

    // ---- preload x A-frags (rows pr..pr+63, full K=256) into registers ----
    bf16x8 xa[4][8];
#pragma unroll
    for (int i = 0; i < 4; ++i)
#pragma unroll
        for (int kk = 0; kk < 8; ++kk)
            xa[i][kk] = *(const bf16x8*)(xb + (size_t)(row0 + pr + i * 16 + lm) * 256
                                            + kk * 32 + quad * 8);

    f32x4 acc[4][4];
#pragma unroll
    for (int i = 0; i < 4; ++i)
#pragma unroll
        for (int j = 0; j < 4; ++j)
            acc[i][j] = (f32x4){0.f, 0.f, 0.f, 0.f};

    // ---- weight chunk staging: linear LDS dest, pre-swizzled global src ----
    auto stageW = [&](int c, int buf) {
        const ushort_t* g1 = W1 + (size_t)c * 64 * 256;
#pragma unroll
        for (int t = 0; t < 4; ++t) {
            int idx = t * 512 + tid;                 // 16B chunk id, 0..2047
            int s1  = idx ^ ((idx >> 5) & 7);        // swizzled source unit
            gld_lds16(g1 + (size_t)s1 * 8, &W1c[buf][(size_t)(t * 512 + wave * 64) * 8]);
        }
#pragma unroll
        for (int t = 0; t < 4; ++t) {
            int idx = t * 512 + tid;                 // row=idx>>3, k8=idx&7
            int k8  = (idx & 7) ^ ((idx >> 3) & 7);  // swizzled k-slot
            const ushort_t* g2 = W2 + (size_t)(idx >> 3) * 2048 + c * 64 + k8 * 8;
            gld_lds16(g2, &W2c[buf][(size_t)(t * 512 + wave * 64) * 8]);
        }
    };

    stageW(0, 0);
    __syncthreads();

    for (int c = 0; c < 32; ++c) {
        const int cur = c & 1;
        if (c + 1 < 32) stageW(c + 1, cur ^ 1);   // async prefetch

        // ---- FF1: p = x @ W1c^T for this wave's 64x16 P-tile ----
        f32x4 p[4];
#pragma unroll
        for (int i = 0; i < 4; ++i)
            p[i] = (f32x4){0.f, 0.f, 0.f, 0.f};

#pragma unroll
        for (int kk = 0; kk < 8; ++kk) {
            bf16x8 wb = *(const bf16x8*)&W1c[cur][((pc + lm) * 256 + kk * 32 + quad * 8) ^ sw];
#pragma unroll
            for (int i = 0; i < 4; ++i)
                p[i] = __builtin_amdgcn_mfma_f32_16x16x32_bf16(xa[i][kk], wb, p[i], 0, 0, 0);
        }

        const int hb = c * 64;
        {
            float bv = bf2f(b1[hb + pc + lm]);
#pragma unroll
            for (int i = 0; i < 4; ++i)
#pragma unroll
                for (int r = 0; r < 4; ++r)
                    Ps[(pr + i * 16 + quad * 4 + r) * 72 + pc + lm] =
                        f2bf(fmaxf(p[i][r] + bv, 0.f));
        }
        __syncthreads();   // Ps visible; prefetch DMA drained

        // ---- FF2: acc += P @ W2c^T ----
#pragma unroll
        for (int ks = 0; ks < 2; ++ks) {
            bf16x8 pa[4];
#pragma unroll
            for (int i = 0; i < 4; ++i)
                pa[i] = *(const bf16x8*)&Ps[(fr + i * 16 + lm) * 72 + ks * 32 + quad * 8];
#pragma unroll
            for (int j = 0; j < 4; ++j) {
                bf16x8 w2b = *(const bf16x8*)&W2c[cur][((fc + j * 16 + lm) * 64 + ks * 32 + quad * 8) ^ sw];
#pragma unroll
                for (int i = 0; i < 4; ++i)
                    acc[i][j] = __builtin_amdgcn_mfma_f32_16x16x32_bf16(pa[i], w2b, acc[i][j], 0, 0, 0);
            }
        }
        __syncthreads();   // Ps + W buf[cur] free for next iteration
    }

    // ---- fused LN2 epilogue ----
    float* Pf = (float*)Ps;           // [128 rows][4 cg][2] floats = 4 KB

    float b2v[4];
#pragma unroll
    for (int j = 0; j < 4; ++j)
        b2v[j] = bf2f(b2[fc + j * 16 + lm]);

    // pass 1: v = xf + acc + b2; per-row partial sums -> LDS
#pragma unroll
    for (int i = 0; i < 4; ++i) {
#pragma unroll
        for (int r = 0; r < 4; ++r) {
            int lrow = fr + i * 16 + quad * 4 + r;
            size_t gbase = (size_t)(row0 + lrow) * 256;
            float s = 0.f, ss = 0.f;
#pragma unroll
            for (int j = 0; j < 4; ++j) {
                float v = xf[gbase + fc + j * 16 + lm] + acc[i][j][r] + b2v[j];
                acc[i][j][r] = v;
                s += v; ss += v * v;
            }
#pragma unroll
            for (int o = 1; o < 16; o <<= 1) {
                s  += __shfl_xor(s,  o, 64);
                ss += __shfl_xor(ss, o, 64);
            }
            if (lm == 0) {
                Pf[(lrow * 4 + cg) * 2]     = s;
                Pf[(lrow * 4 + cg) * 2 + 1] = ss;
            }
        }
    }
    __syncthreads();

    float lsv[4], lbv[4];
#pragma unroll
    for (int j = 0; j < 4; ++j) {
        lsv[j] = bf2f(ls[fc + j * 16 + lm]);
        lbv[j] = bf2f(lb[fc + j * 16 + lm]);
    }

    // pass 2: finalize LN2; write xf (+ x_b for non-final layers)
#pragma unroll
    for (int i = 0; i < 4; ++i) {
#pragma unroll
        for (int r = 0; r < 4; ++r) {
            int lrow = fr + i * 16 + quad * 4 + r;
            float S = 0.f, SS = 0.f;
#pragma unroll
            for (int c4 = 0; c4 < 4; ++c4) {
                S  += Pf[(lrow * 4 + c4) * 2];
                SS += Pf[(lrow * 4 + c4) * 2 + 1];
            }
            float mu   = S * (1.f / 256.f);
            float var  = SS * (1.f / 256.f) - mu * mu;
            float rstd = rsqrtf(var + 1e-5f);
            size_t gbase = (size_t)(row0 + lrow) * 256;
#pragma unroll
            for (int j = 0; j < 4; ++j) {
                float y = (acc[i][j][r] - mu) * rstd * lsv[j] + lbv[j];
                size_t idx = gbase + fc + j * 16 + lm;
                xf[idx] = y;
                if (!is_final) xb_out[idx] = f2bf(y);
            }
        }
    }
}

// ---------------------------------------------------------------------------
// MFMA block-diagonal attention, wave-per-head, zero block barriers.
// ---------------------------------------------------------------------------
__constant__ int c_starts[6] = {0, 50, 67, 84, 101, 151};

__global__ __launch_bounds__(256)
void attn_kernel(ushort_t* __restrict__ qkv)
{
    alignas(16) __shared__ ushort_t Vt[4][32 * 72];  // V^T: [dh][key]
    alignas(16) __shared__ ushort_t Pss[4][16 * 72]; // P strip: [row][key]

    const int b    = blockIdx.x / 5;
    const int blk  = blockIdx.x % 5;
    const int a0   = c_starts[blk];
    const int n    = c_starts[blk + 1] - a0;
    const int wave = threadIdx.x >> 6;
    const int lane = threadIdx.x & 63;
    const int lm   = lane & 15;
    const int quad = lane >> 4;
    const float scale = 0.17677669529663687f;  // 1/sqrt(32)

    const size_t rowbase = (size_t)b * L_ + a0;

    for (int hi = 0; hi < 2; ++hi) {
        const int h = wave + hi * 4;
        const int hoff = h * 32;

#pragma unroll
        for (int it = 0; it < 4; ++it) {
            int gidx = it * 64 + lane;
            int c    = gidx >> 2;
            int dcc  = (gidx & 3) * 8;
            us8 v = *(const us8*)(qkv + (rowbase + c) * 768 + 512 + hoff + dcc);
            if (c >= n) v = (us8){0,0,0,0,0,0,0,0};
#pragma unroll
            for (int j = 0; j < 8; ++j)
                Vt[wave][(dcc + j) * 72 + c] = v[j];
        }

        bf16x8 kb[4];
#pragma unroll
        for (int j = 0; j < 4; ++j)
            kb[j] = *(const bf16x8*)(qkv + (rowbase + 16 * j + lm) * 768 + 256 + hoff + quad * 8);

        bf16x8 vb[2][2];
#pragma unroll
        for (int t = 0; t < 2; ++t)
#pragma unroll
            for (int kc = 0; kc < 2; ++kc)
                vb[t][kc] = *(const bf16x8*)&Vt[wave][(16 * t + lm) * 72 + kc * 32 + quad * 8];

        for (int i = 0; i < 4 && 16 * i < n; ++i) {
            bf16x8 qa = *(const bf16x8*)(qkv + (rowbase + 16 * i + lm) * 768 + hoff + quad * 8);

            f32x4 s[4];
#pragma unroll
            for (int j = 0; j < 4; ++j)
                s[j] = __builtin_amdgcn_mfma_f32_16x16x32_bf16(
                    qa, kb[j], (f32x4){0.f, 0.f, 0.f, 0.f}, 0, 0, 0);

#pragma unroll
            for (int j = 0; j < 4; ++j) {
                bool valid = (16 * j + lm) < n;
#pragma unroll
                for (int r = 0; r < 4; ++r)
                    s[j][r] = valid ? s[j][r] * scale : -1e30f;
            }

            float inv[4];
#pragma unroll
            for (int r = 0; r < 4; ++r) {
                float mx = fmaxf(fmaxf(s[0][r], s[1][r]), fmaxf(s[2][r], s[3][r]));
#pragma unroll
                for (int o2 = 1; o2 < 16; o2 <<= 1) mx = fmaxf(mx, __shfl_xor(mx, o2, 64));
                float sum = 0.f;
#pragma unroll
                for (int j = 0; j < 4; ++j) {
                    float ev = __expf(s[j][r] - mx);
                    s[j][r] = ev;
                    sum += ev;
                }
#pragma unroll
                for (int o2 = 1; o2 < 16; o2 <<= 1) sum += __shfl_xor(sum, o2, 64);
                inv[r] = 1.0f / sum;
            }

#pragma unroll
            for (int j = 0; j < 4; ++j)
#pragma unroll
                for (int r = 0; r < 4; ++r)
                    Pss[wave][(quad * 4 + r) * 72 + 16 * j + lm] = f2bf(s[j][r]);

            bf16x8 pa0 = *(const bf16x8*)&Pss[wave][lm * 72 + quad * 8];
            bf16x8 pa1 = *(const bf16x8*)&Pss[wave][lm * 72 + 32 + quad * 8];

            f32x4 o[2];
#pragma unroll
            for (int t = 0; t < 2; ++t) {
                o[t] = __builtin_amdgcn_mfma_f32_16x16x32_bf16(
                    pa0, vb[t][0], (f32x4){0.f, 0.f, 0.f, 0.f}, 0, 0, 0);
                o[t] = __builtin_amdgcn_mfma_f32_16x16x32_bf16(
                    pa1, vb[t][1], o[t], 0, 0, 0);
            }

#pragma unroll
            for (int r = 0; r < 4; ++r) {
                int m = 16 * i + quad * 4 + r;
                if (m < n) {
#pragma unroll
                    for (int t = 0; t < 2; ++t)
                        qkv[(rowbase + m) * 768 + hoff + 16 * t + lm] =
                            f2bf(o[t][r] * inv[r]);
                }
            }
        }
    }
}

// ---------------------------------------------------------------------------
// Workspace: x_f32 39.58MB | U 59.38MB | Wbf 15.78MB | flag = ~114.8MB.
// x_b bf16 residual copy lives in d_out; cvt_out writes the real answer.
// ---------------------------------------------------------------------------
extern "C" void kernel_launch(void* const* d_in, const int* in_sizes, int n_in,
                              void* d_out, int out_size, void* d_ws, size_t ws_size,
                              hipStream_t stream)
{
    char* ws = (char*)d_ws;
    size_t o = 0;
    float*    x_f32 = (float*)(ws + o);    o += (size_t)M_ * D_ * 4;
    ushort_t* U     = (ushort_t*)(ws + o); o += (size_t)M_ * 768 * 2;
    ushort_t* Wbf   = (ushort_t*)(ws + o); o += (size_t)WTOT * 2;
    int*      flag  = (int*)(ws + o);      o += 256;
    ushort_t* x_b   = (ushort_t*)d_out;
    (void)ws_size; (void)in_sizes; (void)n_in; (void)out_size;

    detect_kernel<<<1, 256, 0, stream>>>((const unsigned int*)d_in[0], flag);

    WPtrs wp;
    for (int a = 0; a < 12; ++a) wp.p[a] = d_in[a + 1];
    cvt_all_kernel<<<(WTOT + 255) / 256, 256, 0, stream>>>(wp, flag, Wbf);

    const ushort_t* qkv_w = Wbf + 0;
    const ushort_t* qkv_b = Wbf + 1179648;
    const ushort_t* out_w = Wbf + 1184256;
    const ushort_t* out_b = Wbf + 1577472;
    const ushort_t* ff1_w = Wbf + 1579008;
    const ushort_t* ff1_b = Wbf + 4724736;
    const ushort_t* ff2_w = Wbf + 4737024;
    const ushort_t* ff2_b = Wbf + 7882752;
    const ushort_t* ln1_s = Wbf + 7884288;
    const ushort_t* ln1_b = Wbf + 7885824;
    const ushort_t* ln2_s = Wbf + 7887360;
    const ushort_t* ln2_b = Wbf + 7888896;

    cvt_src_kernel<<<(M_ * D_) / 256, 256, 0, stream>>>(d_in[0], flag, x_f32, x_b);

    for (int i = 0; i < NL_; ++i) {
        // QKV projection -> U [M,768] bf16 (128x256 tile, 512 thr)
        qkv_gemm<<<dim3(3, M_ / 128), 512, 0, stream>>>(
            x_b, qkv_w + (size_t)i * 768 * D_, qkv_b + (size_t)i * 768, U);
        // MFMA block-diagonal attention; ctx overwrites q columns of U
        attn_kernel<<<B_ * 5, 256, 0, stream>>>(U);
        // out projection + residual + fused LN1: xf = LN1(xf + ctx@W^T + b)
        oproj_ln_kernel<<<M_ / 128, 512, 0, stream>>>(
            U, out_w + (size_t)i * D_ * D_, out_b + (size_t)i * D_, x_f32,
            ln1_s + (size_t)i * D_, ln1_b + (size_t)i * D_, x_b);
        // fused FFN + LN2: xf = LN2(xf + W2@relu(W1@x_b+b1)+b2)
        ffn_kernel<<<M_ / 128, 512, 0, stream>>>(
            x_b, ff1_w + (size_t)i * FF_ * D_, ff1_b + (size_t)i * FF_,
            ff2_w + (size_t)i * D_ * FF_, ff2_b + (size_t)i * D_, x_f32,
            ln2_s + (size_t)i * D_, ln2_b + (size_t)i * D_,
            x_b, (i == NL_ - 1) ? 1 : 0);
    }
    // final output conversion (after ALL x_b reads are complete)
    cvt_out_kernel<<<(M_ * D_) / 1024, 256, 0, stream>>>(x_f32, flag, d_out);
}